// Round 4
// baseline (18.941 us; speedup 1.0000x reference)
//
#include <hip/hip_runtime.h>
#include <stdint.h>

#define TSTEPS 6
#define BB 512
#define SS 40
#define VV 28
#define NPK 512
#define NION 111
#define NB_CE 1920            // 1920 * 64 rows = 122880 = T*B*S
#define NBLK (NB_CE + BB)     // 2432

#define PROTON 1.007276f
#define WATER 18.010565f
#define CO 27.994915f

// ---------------- block reduction helper ----------------
__device__ __forceinline__ float blockReduceSum(float v, float* red) {
#pragma unroll
  for (int off = 32; off > 0; off >>= 1) v += __shfl_down(v, off);
  int lane = threadIdx.x & 63, wid = threadIdx.x >> 6;
  if (lane == 0) red[wid] = v;
  __syncthreads();
  int nw = (blockDim.x + 63) >> 6;
  v = (threadIdx.x < nw) ? red[threadIdx.x] : 0.0f;
  if (wid == 0) {
#pragma unroll
    for (int off = 32; off > 0; off >>= 1) v += __shfl_down(v, off);
  }
  return v;  // valid in thread 0
}

// ---------------- bool-dtype detection (single wave, one ballot) -------------
// 4-byte-word masks (int/fp 0/1) have byte1 == 0 in every word; 1-byte numpy
// bools (70-80% true) make ballot nonzero with P(miss) <= 0.3^64 ~ 1e-33.
__device__ __forceinline__ int detectBoolFlag64(const uint8_t* __restrict__ bytes,
                                                int* s_fl) {
  if (threadIdx.x < 64) {
    unsigned long long b = __ballot(bytes[4 * threadIdx.x + 1] != 0);
    if (threadIdx.x == 0) *s_fl = (b != 0ull) ? 1 : 0;
  }
  __syncthreads();
  return *s_fl;
}

// ---------------- fused CE + spectrum ----------------
// blocks [0, NB_CE): CE, 64 rows each, 4 lanes/row.
//   partial[2i] = sum w*(lse-row[tgt])*mf ; partial[2i+1] = sum mf (t==0 rows)
// blocks [NB_CE, NBLK): spectrum, b = blk - NB_CE.
//   partial[2i] = sum matched*iw*nm ; partial[2i+1] = sum nm
__global__ void __launch_bounds__(256) k_fused(
    const float* __restrict__ logits,   // (T,B,S,V)
    const int* __restrict__ targets,    // (B,S)
    const uint8_t* __restrict__ tmask8, // (B,S)
    const float* __restrict__ obs_m,    // (B,NPK) sorted
    const float* __restrict__ obs_i,    // (B,NPK)
    const uint8_t* __restrict__ pmask8, // (B,NPK)
    const float* __restrict__ aa,       // (V,)
    float* __restrict__ partial) {
  __shared__ float red[8];
  __shared__ int s_fl;
  const int tid = threadIdx.x;

  if (blockIdx.x < NB_CE) {
    // ================= CE path: 4 lanes per row =================
    const int row_id = blockIdx.x * 64 + (tid >> 2);
    const int j = tid & 3;
    const int t = row_id / (BB * SS);
    const int bs = row_id - t * (BB * SS);
    const float4* g4 = (const float4*)logits + (size_t)row_id * 7;
    // lane j: float4 #j and #(j+4); lane 3's second is a duplicate of #3
    // (harmless for max, weighted 0 in the exp sum).
    float4 v1 = g4[j];
    float4 v2 = g4[(j < 3) ? j + 4 : 3];
    int tgt = targets[bs];
    const int fl = detectBoolFlag64(tmask8, &s_fl);  // overlaps load latency
    bool msk = fl ? (tmask8[bs] != 0) : (((const uint32_t*)tmask8)[bs] != 0u);
    float mf = msk ? 1.0f : 0.0f;

    float m = fmaxf(fmaxf(v1.x, v1.y), fmaxf(v1.z, v1.w));
    m = fmaxf(m, fmaxf(fmaxf(v2.x, v2.y), fmaxf(v2.z, v2.w)));
    m = fmaxf(m, __shfl_xor(m, 1));
    m = fmaxf(m, __shfl_xor(m, 2));

    float w2 = (j < 3) ? 1.0f : 0.0f;
    float se = __expf(v1.x - m) + __expf(v1.y - m) + __expf(v1.z - m) + __expf(v1.w - m);
    se += w2 * (__expf(v2.x - m) + __expf(v2.y - m) + __expf(v2.z - m) + __expf(v2.w - m));
    se += __shfl_xor(se, 1);
    se += __shfl_xor(se, 2);
    float lse = m + __logf(se);

    // row[tgt]: float4 f = tgt>>2, slot = tgt&3; held as v1 (j==f) or v2 (j==f-4)
    float ce_c = 0.0f, mf_c = 0.0f;
    if (tgt != 0) {
      const float w = (float)(t + 1) * (1.0f / 21.0f);
      int f = tgt >> 2, sl = tgt & 3;
      float cand = 0.0f;
      if (j == f) {
        cand = (sl == 0) ? v1.x : (sl == 1) ? v1.y : (sl == 2) ? v1.z : v1.w;
      } else if (f >= 4 && j == f - 4) {
        cand = (sl == 0) ? v2.x : (sl == 1) ? v2.y : (sl == 2) ? v2.z : v2.w;
      }
      ce_c = w * mf * (((j == 0) ? lse : 0.0f) - cand);
    }
    if (t == 0 && j == 0) mf_c = mf;

    float s1 = blockReduceSum(ce_c, red);
    __syncthreads();
    float s2 = blockReduceSum(mf_c, red);
    if (tid == 0) {
      partial[2 * blockIdx.x] = s1;
      partial[2 * blockIdx.x + 1] = s2;
    }
  } else {
    // ================= spectrum path =================
    __shared__ float s_mass[NPK];
    __shared__ float s_int[NPK];     // negative => masked-out peak
    __shared__ float s_logit[SS * VV];
    __shared__ float s_exp[SS];
    __shared__ float s_theo[NION + 1];
    __shared__ float s_aa[VV];
    const int b = blockIdx.x - NB_CE;

    // issue all heavy loads before the flag ballot so latencies overlap
    float m1 = obs_m[(size_t)b * NPK + tid];
    float m2 = obs_m[(size_t)b * NPK + 256 + tid];
    float i1 = obs_i[(size_t)b * NPK + tid];
    float i2 = obs_i[(size_t)b * NPK + 256 + tid];
    {
      const float4* g4 = (const float4*)(logits +
          (size_t)(TSTEPS - 1) * BB * SS * VV + (size_t)b * SS * VV);
      float4* l4 = (float4*)s_logit;
      l4[tid] = g4[tid];
      if (tid < 24) l4[256 + tid] = g4[256 + tid];  // 280 total
    }
    if (tid < VV) s_aa[tid] = aa[tid];

    const int fl = detectBoolFlag64(pmask8, &s_fl);
    bool pm1 = fl ? (pmask8[(size_t)b * NPK + tid] != 0)
                  : (((const uint32_t*)pmask8)[(size_t)b * NPK + tid] != 0u);
    bool pm2 = fl ? (pmask8[(size_t)b * NPK + 256 + tid] != 0)
                  : (((const uint32_t*)pmask8)[(size_t)b * NPK + 256 + tid] != 0u);
    s_mass[tid] = m1;
    s_mass[256 + tid] = m2;
    s_int[tid] = pm1 ? i1 : -1.0f;
    s_int[256 + tid] = pm2 ? i2 : -1.0f;
    __syncthreads();

    // expected mass per position: softmax(final logits) . aa
    if (tid < SS) {
      const float* row = s_logit + tid * VV;
      float m = -1e30f;
#pragma unroll
      for (int v = 0; v < VV; v++) m = fmaxf(m, row[v]);
      float se = 0.0f, sw = 0.0f;
#pragma unroll
      for (int v = 0; v < VV; v++) {
        float e = __expf(row[v] - m);
        se += e;
        sw += e * s_aa[v];
      }
      s_exp[tid] = sw / se;
    }
    __syncthreads();

    // theoretical ions (38-element serial scans; negligible)
    if (tid == 0) {
      float c = 0.0f;
#pragma unroll
      for (int j = 0; j < 37; j++) {
        c += s_exp[1 + j];
        s_theo[j] = c + PROTON;             // b ions
        s_theo[74 + j] = c + PROTON - CO;   // a ions
      }
      float c2 = 0.0f;
#pragma unroll
      for (int j = 37; j >= 0; j--) {
        c2 += s_exp[1 + j];
        if (j <= 36) s_theo[37 + j] = c2 + WATER + PROTON;  // y ions
      }
    }
    __syncthreads();

    float contrib = 0.0f, cnt = 0.0f;
    if (tid < NION) {
      const float th = s_theo[tid];
      // binary search: first index with mass > th - 0.5
      const float lim = th - 0.5f;
      int lo = 0, hi = NPK;
      while (lo < hi) {
        int mid = (lo + hi) >> 1;
        if (s_mass[mid] <= lim) lo = mid + 1; else hi = mid;
      }
      // walk the tiny window; scores in [-5,0] so direct exp is exact-stable
      float se = 0.0f, sh = 0.0f, si = 0.0f;
      int has = 0;
      for (int p = lo; p < NPK; ++p) {
        float ms = s_mass[p];
        if (!(ms < th + 0.5f)) break;
        float iv = s_int[p];
        if (iv < 0.0f) continue;  // masked peak
        float d = fabsf(th - ms);
        if (!(d < 0.5f)) continue;
        float e = __expf(-10.0f * d);
        float hub = (d <= 0.2f) ? (0.5f * d * d) : (0.2f * (d - 0.1f));
        se += e; sh += e * hub; si += e * iv;
        has = 1;
      }
      if (has) {
        contrib = (sh / se) * (si / se);
        cnt = 1.0f;
      }
    }
    float s1 = blockReduceSum(contrib, red);
    __syncthreads();
    float s2 = blockReduceSum(cnt, red);
    if (tid == 0) {
      partial[2 * blockIdx.x] = s1;
      partial[2 * blockIdx.x + 1] = s2;
    }
  }
}

// ---------------- final reduce + combine ----------------
__global__ void __launch_bounds__(256) k_final(const float* __restrict__ partial,
                                               float* __restrict__ out) {
  __shared__ float red[8];
  float a0 = 0.0f, a1 = 0.0f, a2 = 0.0f, a3 = 0.0f;
  for (int i = threadIdx.x; i < NB_CE; i += 256) {
    a0 += partial[2 * i];
    a1 += partial[2 * i + 1];
  }
  for (int i = NB_CE + threadIdx.x; i < NBLK; i += 256) {
    a2 += partial[2 * i];
    a3 += partial[2 * i + 1];
  }
  a0 = blockReduceSum(a0, red); __syncthreads();
  a1 = blockReduceSum(a1, red); __syncthreads();
  a2 = blockReduceSum(a2, red); __syncthreads();
  a3 = blockReduceSum(a3, red);
  if (threadIdx.x == 0) {
    float ce = a0 / fmaxf(a1, 1.0f);
    float spec = a2 / fmaxf(a3, 1.0f);
    out[0] = ce + 0.1f * spec;
  }
}

extern "C" void kernel_launch(void* const* d_in, const int* in_sizes, int n_in,
                              void* d_out, int out_size, void* d_ws, size_t ws_size,
                              hipStream_t stream) {
  const float* all_logits = (const float*)d_in[0];
  const int* targets = (const int*)d_in[1];
  const uint8_t* target_mask = (const uint8_t*)d_in[2];
  const float* obs_m = (const float*)d_in[3];
  const float* obs_i = (const float*)d_in[4];
  const uint8_t* peak_mask = (const uint8_t*)d_in[5];
  const float* aa = (const float*)d_in[6];
  float* out = (float*)d_out;

  float* partial = (float*)d_ws;  // NBLK*2 floats, fully overwritten each call

  k_fused<<<NBLK, 256, 0, stream>>>(all_logits, targets, target_mask,
                                    obs_m, obs_i, peak_mask, aa, partial);
  k_final<<<1, 256, 0, stream>>>(partial, out);
}